// Round 2
// baseline (473.802 us; speedup 1.0000x reference)
//
#include <hip/hip_runtime.h>

#define H_ 128
#define W_ 160
#define HW_ (H_ * W_)
#define CAP_ 128            // max events per (b,src) bin; Poisson(48.8) P(>=128) ~ 1e-19
#define INVALID_ 0xFFFFFFFFu

// ---------------------------------------------------------------------------
// Pass A: counting-sort events into (b, src) bins. Only ts+polarity (4 B,
// polarity in the sign bit — ts in [0,1) so bit31 is free) is stored.
// ---------------------------------------------------------------------------
__global__ __launch_bounds__(256) void bin_events(
    const float4* __restrict__ ev,   // (B, N, 4): ts, y, x, p
    unsigned* __restrict__ cnt,      // (B*HW) counters, pre-zeroed
    unsigned* __restrict__ bins,     // (B*HW, CAP_) packed ts|polsign
    int N)
{
    int i = blockIdx.x * blockDim.x + threadIdx.x;
    int b = blockIdx.y;
    if (i >= N) return;

    float4 e = ev[(size_t)b * N + i];
    int src = (int)e.y * W_ + (int)e.z;          // y,x are exact small ints
    unsigned bin = (unsigned)b * HW_ + (unsigned)src;
    unsigned slot = atomicAdd(&cnt[bin], 1u);
    if (slot < CAP_) {
        unsigned v = __float_as_uint(e.x) | ((e.w < 0.0f) ? 0x80000000u : 0u);
        bins[(size_t)bin * CAP_ + slot] = v;
    }
}

// ---------------------------------------------------------------------------
// Pass B: one wave per bin. All events in a bin share (y, x, fy, fx); only ts
// and polarity vary. Recompute fw bit-exactly, scatter-add to out, and count
// first occurrences of (pol, fw) within the bin via an LDS O(n^2/64) scan —
// this IS the distinct-(pol,src,fw) count, since src is fixed per bin.
// ---------------------------------------------------------------------------
__global__ __launch_bounds__(256) void process_bins(
    const unsigned* __restrict__ bins,
    const unsigned* __restrict__ cnt,
    const float* __restrict__ flow,   // (B, 2, HW): ch0 = fx, ch1 = fy
    float* __restrict__ out,          // (B, 2, HW), pre-zeroed
    unsigned* __restrict__ contrib)   // (B, 2, HW), pre-zeroed
{
    const int wave = threadIdx.x >> 6;             // 4 waves per block
    const int lane = threadIdx.x & 63;
    const int bin  = blockIdx.x * 4 + wave;        // < B*HW by construction
    const int b    = bin / HW_;
    const int src  = bin - b * HW_;

    __shared__ unsigned keys[4][CAP_];

    const unsigned n = min(cnt[bin], (unsigned)CAP_);
    const float yf = (float)(src / W_);
    const float xf = (float)(src % W_);
    const float* fl = flow + (size_t)b * 2 * HW_;
    const float fx = fl[src];                      // flow channel 0 (x)
    const float fy = fl[HW_ + src];                // flow channel 1 (y)
    const unsigned* myb = bins + (size_t)bin * CAP_;
    float* outb = out + (size_t)b * 2 * HW_;

    // Phase 1: compute fw per event, scatter-add out, stash (pol,fw) key.
    for (unsigned i = lane; i < n; i += 64) {
        unsigned v = myb[i];
        float ts = __uint_as_float(v & 0x7FFFFFFFu);
        unsigned c = v >> 31;                      // 0 = pos, 1 = neg

        // Bit-exact numpy op order: y + ((1 - ts) * f) * 160, no FMA.
        float dt = __fsub_rn(1.0f, ts);
        float wy = __fadd_rn(yf, __fmul_rn(__fmul_rn(dt, fy), 160.0f));
        float wx = __fadd_rn(xf, __fmul_rn(__fmul_rn(dt, fx), 160.0f));
        float ry = rintf(wy);                      // round half to even
        float rx = rintf(wx);

        unsigned key = INVALID_;
        if (ry >= 0.0f && ry < (float)H_ && rx >= 0.0f && rx < (float)W_) {
            int fw = (int)ry * W_ + (int)rx;
            key = (c << 15) | (unsigned)fw;        // fw < 2^15
            atomicAdd(&outb[c * HW_ + fw], 1.0f);  // fire-and-forget
        }
        keys[wave][i] = key;
    }
    __syncthreads();

    // Phase 2: first-occurrence scan (wave-private LDS region).
    for (unsigned i = lane; i < n; i += 64) {
        unsigned k = keys[wave][i];
        if (k == INVALID_) continue;
        bool first = true;
        for (unsigned j = 0; j < i; ++j) {
            if (keys[wave][j] == k) { first = false; break; }
        }
        if (first) {
            unsigned c = k >> 15, fw = k & 0x7FFFu;
            atomicAdd(&contrib[((size_t)b * 2 + c) * HW_ + fw], 1u);
        }
    }
}

__global__ __launch_bounds__(256) void iwe_div(
    float* __restrict__ out, const unsigned* __restrict__ contrib, int n)
{
    int i = blockIdx.x * blockDim.x + threadIdx.x;
    if (i < n) {
        unsigned c = contrib[i];
        if (c > 0u) out[i] = __fdiv_rn(out[i], (float)c);
    }
}

extern "C" void kernel_launch(void* const* d_in, const int* in_sizes, int n_in,
                              void* d_out, int out_size, void* d_ws, size_t ws_size,
                              hipStream_t stream) {
    const float*  flow = (const float*)d_in[0];
    const float4* ev   = (const float4*)d_in[1];
    // d_in[2] (pol_mask) is redundant with event_list's p column — not read.

    int B = in_sizes[0] / (2 * HW_);          // = 4
    int N = in_sizes[1] / (B * 4);            // = 1,000,000

    // Workspace: [contrib: out_size u32][cnt: B*HW u32][bins: B*HW*CAP u32]
    unsigned* contrib = (unsigned*)d_ws;
    unsigned* cnt     = contrib + out_size;
    unsigned* binsbuf = cnt + (size_t)B * HW_;

    hipMemsetAsync(d_out, 0, (size_t)out_size * sizeof(float), stream);
    hipMemsetAsync(contrib, 0, (size_t)out_size * sizeof(unsigned), stream);
    hipMemsetAsync(cnt, 0, (size_t)B * HW_ * sizeof(unsigned), stream);
    // binsbuf needs no init: cnt defines the valid prefix of each bin.

    dim3 gridA((N + 255) / 256, B);
    bin_events<<<gridA, 256, 0, stream>>>(ev, cnt, binsbuf, N);

    int nbins = B * HW_;                       // 81920, divisible by 4
    process_bins<<<nbins / 4, 256, 0, stream>>>(binsbuf, cnt, flow,
                                                (float*)d_out, contrib);

    iwe_div<<<(out_size + 255) / 256, 256, 0, stream>>>((float*)d_out, contrib,
                                                        out_size);
}

// Round 3
// 308.891 us; speedup vs baseline: 1.5339x; 1.5339x over previous
//
#include <hip/hip_runtime.h>

#define H_ 128
#define W_ 160
#define HW_ (H_ * W_)
#define WORDS_ 9   // s = |ry-y| + |rx-x| <= 127+159 = 286 < 9*32 bits

// One thread per event. blockIdx.y = batch.
//
// Dedup trick: for fixed src=(y,x) and flow f, the warped cell
// (ry,rx) = (rint(y+dt*fy*160), rint(x+dt*fx*160)) is componentwise monotone
// in dt, so s = |ry-y|+|rx-x| strictly increases whenever the cell changes:
// s is an injective index for fw given (src,pol), bounded by 286 for valid
// (in-bounds) cells. One atomicOr into a per-(b,src,pol) 288-bit bitmap
// replaces the whole hash-set: old-bit-clear <=> first (pol,src,fw) triple.
__global__ __launch_bounds__(256) void iwe_scatter(
    const float4* __restrict__ ev,      // (B, N, 4): ts, y, x, p
    const float* __restrict__ flow,     // (B, 2, HW): ch0 = fx, ch1 = fy
    float* __restrict__ out,            // (B, 2, HW), pre-zeroed
    unsigned* __restrict__ contrib,     // (B, 2, HW), pre-zeroed
    unsigned* __restrict__ bitmap,      // (B, HW, 2, WORDS_), pre-zeroed
    int N)
{
    int i = blockIdx.x * blockDim.x + threadIdx.x;
    int b = blockIdx.y;
    if (i >= N) return;

    float4 e = ev[(size_t)b * N + i];
    float ts = e.x, yf = e.y, xf = e.z, p = e.w;

    int src = (int)yf * W_ + (int)xf;                 // y,x are exact small ints
    const float* fl = flow + (size_t)b * 2 * HW_;
    float fx = fl[src];          // flow channel 0 (x)
    float fy = fl[HW_ + src];    // flow channel 1 (y)

    // Bit-exact numpy op order: y + ((1 - ts) * f) * 160, no FMA contraction.
    float dt = __fsub_rn(1.0f, ts);
    float wy = __fadd_rn(yf, __fmul_rn(__fmul_rn(dt, fy), 160.0f));
    float wx = __fadd_rn(xf, __fmul_rn(__fmul_rn(dt, fx), 160.0f));

    float ry = rintf(wy);   // round half to even, matches jnp.round/np.round
    float rx = rintf(wx);

    // Validity on the *rounded* floats (so -0.0 counts as valid, like the ref).
    if (!(ry >= 0.0f && ry < (float)H_ && rx >= 0.0f && rx < (float)W_)) return;

    int iy = (int)ry, ix = (int)rx;
    int fw = iy * W_ + ix;
    unsigned c = (p > 0.0f) ? 0u : 1u;                // out channel: 0=pos, 1=neg
    size_t oidx = ((size_t)b * 2 + c) * HW_ + fw;

    atomicAdd(&out[oidx], 1.0f);                      // weight * pol_mask == 1

    int s = abs(iy - (int)yf) + abs(ix - (int)xf);    // injective cell index, <=286
    size_t widx = (((size_t)b * HW_ + src) * 2 + c) * WORDS_ + (s >> 5);
    unsigned bit = 1u << (s & 31);
    unsigned old = atomicOr(&bitmap[widx], bit);
    if (!(old & bit))                                 // first (pol,src,fw) triple
        atomicAdd(&contrib[oidx], 1u);
}

__global__ __launch_bounds__(256) void iwe_div(
    float* __restrict__ out, const unsigned* __restrict__ contrib, int n)
{
    int i = blockIdx.x * blockDim.x + threadIdx.x;
    if (i < n) {
        unsigned c = contrib[i];
        if (c > 0u) out[i] = __fdiv_rn(out[i], (float)c);
    }
}

extern "C" void kernel_launch(void* const* d_in, const int* in_sizes, int n_in,
                              void* d_out, int out_size, void* d_ws, size_t ws_size,
                              hipStream_t stream) {
    const float*  flow = (const float*)d_in[0];
    const float4* ev   = (const float4*)d_in[1];
    // d_in[2] (pol_mask) is redundant with event_list's p column — not read.

    int B = in_sizes[0] / (2 * HW_);          // = 4
    int N = in_sizes[1] / (B * 4);            // = 1,000,000

    // Workspace: [contrib: out_size u32][bitmap: B*HW*2*WORDS_ u32]
    unsigned* contrib = (unsigned*)d_ws;
    unsigned* bitmap  = contrib + out_size;
    size_t bitmapBytes = (size_t)B * HW_ * 2 * WORDS_ * sizeof(unsigned); // ~5.9 MB

    hipMemsetAsync(d_out, 0, (size_t)out_size * sizeof(float), stream);
    hipMemsetAsync(contrib, 0, (size_t)out_size * sizeof(unsigned), stream);
    hipMemsetAsync(bitmap, 0, bitmapBytes, stream);

    dim3 grid((N + 255) / 256, B);
    iwe_scatter<<<grid, 256, 0, stream>>>(ev, flow, (float*)d_out, contrib,
                                          bitmap, N);
    iwe_div<<<(out_size + 255) / 256, 256, 0, stream>>>((float*)d_out, contrib,
                                                        out_size);
}

// Round 4
// 243.387 us; speedup vs baseline: 1.9467x; 1.2691x over previous
//
#include <hip/hip_runtime.h>

#define H_ 128
#define W_ 160
#define HW_ (H_ * W_)
#define WORDS_ 9   // s = |ry-y| + |rx-x| <= 127+159 = 286 < 9*32 bits

// ---------------------------------------------------------------------------
// Pass 0: interleave planar flow (B,2,HW) -> float2 (fx,fy) per pixel, so the
// per-event gather is ONE 8-byte divergent load instead of two 4-byte loads.
// ---------------------------------------------------------------------------
__global__ __launch_bounds__(256) void repack_flow(
    const float* __restrict__ flow,   // (B, 2, HW): ch0 = fx, ch1 = fy
    float2* __restrict__ flow2,       // (B, HW): {fx, fy}
    int total)                        // B*HW
{
    int i = blockIdx.x * blockDim.x + threadIdx.x;
    if (i >= total) return;
    int b = i / HW_, idx = i - b * HW_;
    const float* fl = flow + (size_t)b * 2 * HW_;
    flow2[i] = make_float2(fl[idx], fl[HW_ + idx]);
}

// ---------------------------------------------------------------------------
// Pass 1: one thread per event, 3 divergent transactions total:
//   1 x float2 gather, 1 x atomicOr (dedup bitmap, returning),
//   1 x 64-bit atomicAdd packing {event count | contrib count} for one cell.
//
// Dedup: for fixed src and flow, the warped cell is componentwise monotone in
// dt=1-ts, so s=|dy|+|dx| is injective over visited cells (chain in Z^2),
// s<=286 -> 288-bit bitmap per (b,src,pol). atomicOr old-bit-clear <=> first
// occurrence of the (pol,src,fw) triple.
// ---------------------------------------------------------------------------
__global__ __launch_bounds__(256) void iwe_scatter(
    const float4* __restrict__ ev,                 // (B, N, 4): ts, y, x, p
    const float2* __restrict__ flow2,              // (B, HW)
    unsigned long long* __restrict__ packed,       // (B, 2, HW): lo=count, hi=contrib
    unsigned* __restrict__ bitmap,                 // (B, HW, 2, WORDS_), zeroed
    int N)
{
    int i = blockIdx.x * blockDim.x + threadIdx.x;
    int b = blockIdx.y;
    if (i >= N) return;

    float4 e = ev[(size_t)b * N + i];
    float ts = e.x, yf = e.y, xf = e.z, p = e.w;

    int src = (int)yf * W_ + (int)xf;              // y,x are exact small ints
    float2 f = flow2[(size_t)b * HW_ + src];       // f.x = fx, f.y = fy

    // Bit-exact numpy op order: y + ((1 - ts) * f) * 160, no FMA contraction.
    float dt = __fsub_rn(1.0f, ts);
    float wy = __fadd_rn(yf, __fmul_rn(__fmul_rn(dt, f.y), 160.0f));
    float wx = __fadd_rn(xf, __fmul_rn(__fmul_rn(dt, f.x), 160.0f));

    float ry = rintf(wy);   // round half to even, matches jnp.round/np.round
    float rx = rintf(wx);

    // Validity on the *rounded* floats (so -0.0 counts as valid, like the ref).
    if (!(ry >= 0.0f && ry < (float)H_ && rx >= 0.0f && rx < (float)W_)) return;

    int iy = (int)ry, ix = (int)rx;
    int fw = iy * W_ + ix;
    unsigned c = (p > 0.0f) ? 0u : 1u;             // channel: 0=pos, 1=neg

    int s = abs(iy - (int)yf) + abs(ix - (int)xf); // injective cell index, <=286
    size_t widx = (((size_t)b * HW_ + src) * 2 + c) * WORDS_ + (s >> 5);
    unsigned bit = 1u << (s & 31);
    unsigned old = atomicOr(&bitmap[widx], bit);

    unsigned long long add = 1ull | ((old & bit) ? 0ull : (1ull << 32));
    atomicAdd(&packed[((size_t)b * 2 + c) * HW_ + fw], add);
}

// ---------------------------------------------------------------------------
// Pass 2: unpack {count, contrib} -> averaged IWE. count < 2^24 so (float)cnt
// is exact == the reference's sum of 1.0f weights; division matches np.
// ---------------------------------------------------------------------------
__global__ __launch_bounds__(256) void iwe_final(
    const unsigned long long* __restrict__ packed,
    float* __restrict__ out, int n)
{
    int i = blockIdx.x * blockDim.x + threadIdx.x;
    if (i >= n) return;
    unsigned long long v = packed[i];
    unsigned cnt = (unsigned)v;
    unsigned cb  = (unsigned)(v >> 32);
    float r = (float)cnt;
    if (cb > 0u) r = __fdiv_rn(r, (float)cb);
    out[i] = r;
}

extern "C" void kernel_launch(void* const* d_in, const int* in_sizes, int n_in,
                              void* d_out, int out_size, void* d_ws, size_t ws_size,
                              hipStream_t stream) {
    const float*  flow = (const float*)d_in[0];
    const float4* ev   = (const float4*)d_in[1];
    // d_in[2] (pol_mask) is redundant with event_list's p column — not read.

    int B = in_sizes[0] / (2 * HW_);          // = 4
    int N = in_sizes[1] / (B * 4);            // = 1,000,000

    // Workspace: [packed u64 x out_size][bitmap u32 x B*HW*2*9][flow2 f2 x B*HW]
    unsigned long long* packed = (unsigned long long*)d_ws;
    unsigned* bitmap = (unsigned*)(packed + out_size);
    size_t bitmapWords = (size_t)B * HW_ * 2 * WORDS_;
    float2* flow2 = (float2*)(bitmap + bitmapWords);

    // Single contiguous zero-init for packed + bitmap (flow2 is fully written).
    size_t zeroBytes = (size_t)out_size * 8 + bitmapWords * 4;
    hipMemsetAsync(d_ws, 0, zeroBytes, stream);

    int total = B * HW_;
    repack_flow<<<(total + 255) / 256, 256, 0, stream>>>(flow, flow2, total);

    dim3 grid((N + 255) / 256, B);
    iwe_scatter<<<grid, 256, 0, stream>>>(ev, flow2, packed, bitmap, N);

    iwe_final<<<(out_size + 255) / 256, 256, 0, stream>>>(packed, (float*)d_out,
                                                          out_size);
}

// Round 5
// 235.736 us; speedup vs baseline: 2.0099x; 1.0325x over previous
//
#include <hip/hip_runtime.h>

#define H_ 128
#define W_ 160
#define HW_ (H_ * W_)
#define WORDS_ 9          // s = |dy|+|dx| <= 127+159 = 286 < 9*32 bits
#define T_ 64             // tiles per batch: 2 rows each (H_/2)
#define SRCS_ (2 * W_)    // 320 srcs per tile
#define SEG_CAP_ 16640    // binomial(1e6,1/64): mean 15625, sigma 124 -> +8.2 sigma

// ---------------------------------------------------------------------------
// Pass A: bin events by (b, tile=y>>1). Block-aggregated reservation: LDS
// per-tile counts -> one returning global atomic per (block,tile) -> payload
// stores land contiguously per (block,tile) => line-coalesced scatter.
// Payload u64: lo = ts bits | pol<<31 (ts<1 so bit31 free), hi = (y&1)<<8 | x.
// ---------------------------------------------------------------------------
__global__ __launch_bounds__(1024) void bin_pass(
    const float4* __restrict__ ev,           // (B, N, 4): ts, y, x, p
    unsigned* __restrict__ tails,            // (B*T_), pre-zeroed
    unsigned long long* __restrict__ segs,   // (B*T_, SEG_CAP_)
    int N)
{
    __shared__ unsigned cnt[T_];
    __shared__ unsigned base[T_];
    const int b = blockIdx.y;
    const int i = blockIdx.x * 1024 + threadIdx.x;

    if (threadIdx.x < T_) cnt[threadIdx.x] = 0;
    __syncthreads();

    unsigned t = 0, rank = 0;
    unsigned long long payload = 0;
    const bool valid = i < N;
    if (valid) {
        float4 e = ev[(size_t)b * N + i];
        int iy = (int)e.y, ix = (int)e.z;        // exact small ints
        t = (unsigned)(iy >> 1);
        unsigned lo = __float_as_uint(e.x) | ((e.w < 0.0f) ? 0x80000000u : 0u);
        unsigned hi = (unsigned)(((iy & 1) << 8) | ix);
        payload = ((unsigned long long)hi << 32) | lo;
        rank = atomicAdd(&cnt[t], 1u);           // LDS: rank within block
    }
    __syncthreads();

    if (threadIdx.x < T_) {
        unsigned c = cnt[threadIdx.x];
        base[threadIdx.x] =
            c ? atomicAdd(&tails[b * T_ + threadIdx.x], c) : 0u;
    }
    __syncthreads();

    if (valid) {
        unsigned pos = base[t] + rank;
        if (pos < SEG_CAP_)                      // +8 sigma; effectively never
            segs[((size_t)(b * T_ + t)) * SEG_CAP_ + pos] = payload;
    }
}

// ---------------------------------------------------------------------------
// Pass B: one block per (b,tile). Flow rows + per-(src,pol) dedup bitmap live
// in LDS; the only global scattered op is ONE fire-and-forget 64-bit
// atomicAdd fusing {event count | first-occurrence contrib} per cell.
// Dedup: s=|dy|+|dx| is injective over cells visited by a monotone warp path
// (fixed src, flow), s<=286 -> 288-bit LDS bitmap per (src,pol).
// ---------------------------------------------------------------------------
__global__ __launch_bounds__(512) void process_tiles(
    const float* __restrict__ flow,              // (B, 2, HW): ch0=fx, ch1=fy
    const unsigned* __restrict__ tails,
    const unsigned long long* __restrict__ segs,
    unsigned long long* __restrict__ packed)     // (B,2,HW): lo=cnt, hi=contrib
{
    __shared__ float2 lflow[SRCS_];              // {fx, fy} per tile src
    __shared__ unsigned bmap[SRCS_ * 2 * WORDS_];

    const int bt = blockIdx.x;
    const int b = bt >> 6, t = bt & 63;

    const float* fb = flow + (size_t)b * 2 * HW_ + (size_t)t * SRCS_;
    for (int j = threadIdx.x; j < SRCS_; j += 512)
        lflow[j] = make_float2(fb[j], fb[HW_ + j]);
    for (int j = threadIdx.x; j < SRCS_ * 2 * WORDS_; j += 512)
        bmap[j] = 0u;
    __syncthreads();

    const unsigned n = min(tails[bt], (unsigned)SEG_CAP_);
    const unsigned long long* seg = segs + (size_t)bt * SEG_CAP_;
    unsigned long long* pk = packed + (size_t)b * 2 * HW_;

    for (unsigned i = threadIdx.x; i < n; i += 512) {
        unsigned long long v = seg[i];
        unsigned lo = (unsigned)v, hi = (unsigned)(v >> 32);
        float ts = __uint_as_float(lo & 0x7FFFFFFFu);
        unsigned c = lo >> 31;                   // 0=pos, 1=neg
        int yp = (int)((hi >> 8) & 1u);
        int ix0 = (int)(hi & 0xFFu);
        int iy0 = (t << 1) | yp;
        int srcl = yp * W_ + ix0;

        float2 f = lflow[srcl];                  // f.x = fx, f.y = fy
        float yf = (float)iy0, xf = (float)ix0;  // exact, == original e.y/e.z

        // Bit-exact numpy op order: y + ((1 - ts) * f) * 160, no FMA.
        float dt = __fsub_rn(1.0f, ts);
        float wy = __fadd_rn(yf, __fmul_rn(__fmul_rn(dt, f.y), 160.0f));
        float wx = __fadd_rn(xf, __fmul_rn(__fmul_rn(dt, f.x), 160.0f));
        float ry = rintf(wy);                    // round half to even
        float rx = rintf(wx);
        if (!(ry >= 0.0f && ry < (float)H_ && rx >= 0.0f && rx < (float)W_))
            continue;

        int iy = (int)ry, ix = (int)rx;
        int fw = iy * W_ + ix;
        int s = abs(iy - iy0) + abs(ix - ix0);   // injective cell idx, <=286
        unsigned bit = 1u << (s & 31);
        unsigned old = atomicOr(&bmap[(srcl * 2 + c) * WORDS_ + (s >> 5)], bit);
        unsigned long long add =
            1ull | ((old & bit) ? 0ull : (1ull << 32));
        atomicAdd(&pk[c * HW_ + fw], add);       // fire-and-forget
    }
}

// ---------------------------------------------------------------------------
// Finalize: counts < 2^24 so (float)cnt == reference's sum of 1.0f weights.
// ---------------------------------------------------------------------------
__global__ __launch_bounds__(256) void iwe_final(
    const unsigned long long* __restrict__ packed,
    float* __restrict__ out, int n)
{
    int i = blockIdx.x * blockDim.x + threadIdx.x;
    if (i >= n) return;
    unsigned long long v = packed[i];
    unsigned cnt = (unsigned)v;
    unsigned cb  = (unsigned)(v >> 32);
    float r = (float)cnt;
    if (cb > 0u) r = __fdiv_rn(r, (float)cb);
    out[i] = r;
}

extern "C" void kernel_launch(void* const* d_in, const int* in_sizes, int n_in,
                              void* d_out, int out_size, void* d_ws, size_t ws_size,
                              hipStream_t stream) {
    const float*  flow = (const float*)d_in[0];
    const float4* ev   = (const float4*)d_in[1];
    // d_in[2] (pol_mask) is redundant with event_list's p column — not read.

    int B = in_sizes[0] / (2 * HW_);          // = 4
    int N = in_sizes[1] / (B * 4);            // = 1,000,000

    // Workspace: [packed u64 x out_size][tails u32 x B*T_][segs u64 x B*T_*CAP]
    unsigned long long* packed = (unsigned long long*)d_ws;
    unsigned* tails = (unsigned*)(packed + out_size);
    unsigned long long* segs =
        (unsigned long long*)(tails + (size_t)B * T_);

    size_t zeroBytes = (size_t)out_size * 8 + (size_t)B * T_ * 4;
    hipMemsetAsync(d_ws, 0, zeroBytes, stream);  // packed + tails only

    dim3 gridA((N + 1023) / 1024, B);
    bin_pass<<<gridA, 1024, 0, stream>>>(ev, tails, segs, N);

    process_tiles<<<B * T_, 512, 0, stream>>>(flow, tails, segs, packed);

    iwe_final<<<(out_size + 255) / 256, 256, 0, stream>>>(packed, (float*)d_out,
                                                          out_size);
}

// Round 6
// 150.742 us; speedup vs baseline: 3.1431x; 1.5638x over previous
//
#include <hip/hip_runtime.h>

#define H_ 128
#define W_ 160
#define HW_ (H_ * W_)
#define TILES_ 256        // dst tiles per batch: (row, x-half) = 128 x 2
#define SEG_CAP_ 8192     // events per tile: mean ~3500, cap = 2.3x mean
#define EVB_ 4096         // events per bin_pass block (4 per thread)
#define HASH_ 8192        // LDS hash entries; >= SEG_CAP_ guarantees termination
#define EMPTY_ 0xFFFFFFFFu

__device__ __forceinline__ unsigned mix32(unsigned h) {
    h ^= h >> 16; h *= 0x85ebca6bu;
    h ^= h >> 13; h *= 0xc2b2ae35u;
    h ^= h >> 16;
    return h;
}

// ---------------------------------------------------------------------------
// Pass 0: interleave planar flow -> float2 so the per-event gather is one 8B
// load. flow2[b*HW + src] = {fx, fy}.
// ---------------------------------------------------------------------------
__global__ __launch_bounds__(256) void repack_flow(
    const float* __restrict__ flow, float2* __restrict__ flow2, int total)
{
    int i = blockIdx.x * blockDim.x + threadIdx.x;
    if (i >= total) return;
    int b = i / HW_, idx = i - b * HW_;
    const float* fl = flow + (size_t)b * 2 * HW_;
    flow2[i] = make_float2(fl[idx], fl[HW_ + idx]);
}

// ---------------------------------------------------------------------------
// Pass A: full warp math per event (flow gather is an L2-resident READ — the
// cheap kind of scattered op), drop invalid events, bin the 4B payload
// (src | pol<<15 | x<<16) by dst tile t = row*2 + (x>=80). Block processes
// EVB_ events so per-(block,tile) runs are ~14 payloads = 56B: line-friendly.
// One returning global atomic per (block,tile) reserves the run.
// ---------------------------------------------------------------------------
__global__ __launch_bounds__(1024) void bin_pass(
    const float4* __restrict__ ev,       // (B, N, 4): ts, y, x, p
    const float2* __restrict__ flow2,    // (B, HW)
    unsigned* __restrict__ tails,        // (B*TILES_), pre-zeroed
    unsigned* __restrict__ segs,         // (B*TILES_, SEG_CAP_)
    int N)
{
    __shared__ unsigned cnt[TILES_];
    __shared__ unsigned base[TILES_];
    const int b = blockIdx.y;
    const int i0 = blockIdx.x * EVB_;

    for (int j = threadIdx.x; j < TILES_; j += 1024) cnt[j] = 0u;
    __syncthreads();

    unsigned pay[4], rank[4];
    unsigned short tt[4];
    bool val[4];

#pragma unroll
    for (int k = 0; k < 4; ++k) {
        val[k] = false;
        int i = i0 + k * 1024 + threadIdx.x;
        if (i < N) {
            float4 e = ev[(size_t)b * N + i];
            int src = (int)e.y * W_ + (int)e.z;       // y,x exact small ints
            float2 f = flow2[(size_t)b * HW_ + src];  // {fx, fy}

            // Bit-exact numpy order: y + ((1 - ts) * f) * 160, no FMA.
            float dt = __fsub_rn(1.0f, e.x);
            float wy = __fadd_rn(e.y, __fmul_rn(__fmul_rn(dt, f.y), 160.0f));
            float wx = __fadd_rn(e.z, __fmul_rn(__fmul_rn(dt, f.x), 160.0f));
            float ry = rintf(wy);                     // round half to even
            float rx = rintf(wx);
            // Validity on rounded floats (-0.0 is valid, like the ref).
            if (ry >= 0.0f && ry < (float)H_ && rx >= 0.0f && rx < (float)W_) {
                int iy = (int)ry, ix = (int)rx;
                unsigned c = (e.w > 0.0f) ? 0u : 1u;  // 0=pos, 1=neg
                unsigned t = (unsigned)(iy * 2 + (ix >= 80));
                pay[k] = (unsigned)src | (c << 15) | ((unsigned)ix << 16);
                tt[k] = (unsigned short)t;
                val[k] = true;
                rank[k] = atomicAdd(&cnt[t], 1u);     // LDS rank
            }
        }
    }
    __syncthreads();

    for (int j = threadIdx.x; j < TILES_; j += 1024) {
        unsigned c = cnt[j];
        base[j] = c ? atomicAdd(&tails[b * TILES_ + j], c) : 0u;
    }
    __syncthreads();

#pragma unroll
    for (int k = 0; k < 4; ++k) {
        if (val[k]) {
            unsigned pos = base[tt[k]] + rank[k];
            if (pos < SEG_CAP_)                       // 2.3x mean; ~never
                segs[((size_t)(b * TILES_ + tt[k])) * SEG_CAP_ + pos] = pay[k];
        }
    }
}

// ---------------------------------------------------------------------------
// Pass B: one block per (b, dst tile). Everything in LDS: exact dedup hash
// set on key=(src,pol,x) (no global atomics), count/contrib accumulators per
// cell, then a fused divide + PLAIN global store (each cell owned by exactly
// one block -> no memset of d_out, no finalize kernel).
// Termination: seg has <= SEG_CAP_ = HASH_ events => <= HASH_ distinct keys;
// while key not yet inserted the table has an empty slot => probe terminates.
// ---------------------------------------------------------------------------
__global__ __launch_bounds__(512) void accum_pass(
    const unsigned* __restrict__ tails,
    const unsigned* __restrict__ segs,
    float* __restrict__ out)                          // (B, 2, H, W)
{
    __shared__ unsigned hset[HASH_];                  // 32 KB
    __shared__ unsigned cntl[2 * 80];
    __shared__ unsigned cbl[2 * 80];

    const int bt = blockIdx.x;                        // b*TILES_ + t
    const int b = bt >> 8, t = bt & 255;
    const int row = t >> 1, half = t & 1;

    for (int j = threadIdx.x; j < HASH_; j += 512) hset[j] = EMPTY_;
    if (threadIdx.x < 160) { cntl[threadIdx.x] = 0u; cbl[threadIdx.x] = 0u; }
    __syncthreads();

    const unsigned n = min(tails[bt], (unsigned)SEG_CAP_);
    const unsigned* seg = segs + (size_t)bt * SEG_CAP_;
    volatile unsigned* hv = hset;

    for (unsigned i = threadIdx.x; i < n; i += 512) {
        unsigned key = seg[i];                        // src | pol<<15 | x<<16
        unsigned c = (key >> 15) & 1u;
        unsigned x = (key >> 16) & 0xFFu;
        unsigned cl = c * 80 + (x - (unsigned)half * 80u);

        unsigned h = mix32(key) & (HASH_ - 1);
        for (;;) {
            unsigned cur = hv[h];                     // cheap pre-read
            if (cur == key) break;                    // duplicate triple
            if (cur == EMPTY_) {
                unsigned prev = atomicCAS(&hset[h], EMPTY_, key);
                if (prev == EMPTY_) {                 // first (pol,src,fw)
                    atomicAdd(&cbl[cl], 1u);
                    break;
                }
                if (prev == key) break;               // raced duplicate
            }
            h = (h + 1) & (HASH_ - 1);
        }
        atomicAdd(&cntl[cl], 1u);                     // event count
    }
    __syncthreads();

    if (threadIdx.x < 160) {
        unsigned c = threadIdx.x / 80;
        unsigned xl = threadIdx.x % 80;
        unsigned cnt = cntl[threadIdx.x], cb = cbl[threadIdx.x];
        float r = (float)cnt;                         // cnt < 2^24: exact
        if (cb > 0u) r = __fdiv_rn(r, (float)cb);
        out[((size_t)(b * 2 + c)) * HW_ + row * W_ + half * 80 + xl] = r;
    }
}

extern "C" void kernel_launch(void* const* d_in, const int* in_sizes, int n_in,
                              void* d_out, int out_size, void* d_ws, size_t ws_size,
                              hipStream_t stream) {
    const float*  flow = (const float*)d_in[0];
    const float4* ev   = (const float4*)d_in[1];
    // d_in[2] (pol_mask) is redundant with event_list's p column — not read.

    int B = in_sizes[0] / (2 * HW_);          // = 4
    int N = in_sizes[1] / (B * 4);            // = 1,000,000

    // Workspace: [tails u32 x B*TILES_][segs u32 x B*TILES_*SEG_CAP_][flow2]
    unsigned* tails = (unsigned*)d_ws;
    unsigned* segs  = tails + (size_t)B * TILES_;
    float2*   flow2 = (float2*)(segs + (size_t)B * TILES_ * SEG_CAP_);

    hipMemsetAsync(tails, 0, (size_t)B * TILES_ * sizeof(unsigned), stream);

    int total = B * HW_;
    repack_flow<<<(total + 255) / 256, 256, 0, stream>>>(flow, flow2, total);

    dim3 gridA((N + EVB_ - 1) / EVB_, B);
    bin_pass<<<gridA, 1024, 0, stream>>>(ev, flow2, tails, segs, N);

    accum_pass<<<B * TILES_, 512, 0, stream>>>(tails, segs, (float*)d_out);
}

// Round 7
// 149.515 us; speedup vs baseline: 3.1689x; 1.0082x over previous
//
#include <hip/hip_runtime.h>

#define H_ 128
#define W_ 160
#define HW_ (H_ * W_)
#define TILES_ 256        // dst tiles per batch: (row, x-half) = 128 x 2
#define SEG_CAP_ 8192     // events per tile seg: ~2.5x observed mean (~3300)
#define EVB_ 8192         // events per bin_pass block (8 per thread)
#define HASH_ 8192        // LDS hash entries; >= SEG_CAP_ guarantees termination
#define EMPTY_ 0xFFFFFFFFu

__device__ __forceinline__ unsigned mix32(unsigned h) {
    h ^= h >> 16; h *= 0x85ebca6bu;
    h ^= h >> 13; h *= 0xc2b2ae35u;
    h ^= h >> 16;
    return h;
}

// ---------------------------------------------------------------------------
// Pass 0: interleave planar flow -> float2: one 8B gather per event later.
// ---------------------------------------------------------------------------
__global__ __launch_bounds__(256) void repack_flow(
    const float* __restrict__ flow, float2* __restrict__ flow2, int total)
{
    int i = blockIdx.x * blockDim.x + threadIdx.x;
    if (i >= total) return;
    int b = i / HW_, idx = i - b * HW_;
    const float* fl = flow + (size_t)b * 2 * HW_;
    flow2[i] = make_float2(fl[idx], fl[HW_ + idx]);
}

// ---------------------------------------------------------------------------
// Pass A: warp math per event, drop invalids, then a block-level COUNTING
// SORT by dst tile in LDS (cnt -> prefix scan -> LDS scatter) so the global
// seg flush is linear: consecutive threads write consecutive slots of the
// same tile run (~32 x 4B = 128B) => waves touch ~6-10 lines, not 64.
// Payload: src | pol<<15 | x<<16 | tile<<24 (tile constant per seg, so the
// extra bits don't perturb the dedup key in pass B).
// ---------------------------------------------------------------------------
__global__ __launch_bounds__(1024) void bin_pass(
    const float4* __restrict__ ev,       // (B, N, 4): ts, y, x, p
    const float2* __restrict__ flow2,    // (B, HW)
    unsigned* __restrict__ tails,        // (B*TILES_), pre-zeroed
    unsigned* __restrict__ segs,         // (B*TILES_, SEG_CAP_)
    int N)
{
    __shared__ unsigned cnt[TILES_];
    __shared__ unsigned scan[TILES_];    // inclusive scan of cnt
    __shared__ unsigned base[TILES_];    // global reservation per tile
    __shared__ unsigned buf[EVB_];       // tile-sorted payloads (32 KB)
    __shared__ unsigned stot;

    const int b = blockIdx.y;
    const int i0 = blockIdx.x * EVB_;

    for (int j = threadIdx.x; j < TILES_; j += 1024) cnt[j] = 0u;
    __syncthreads();

    unsigned pay[8], rank[8];
    bool val[8];

#pragma unroll
    for (int k = 0; k < 8; ++k) {
        val[k] = false;
        int i = i0 + k * 1024 + threadIdx.x;
        if (i < N) {
            float4 e = ev[(size_t)b * N + i];
            int src = (int)e.y * W_ + (int)e.z;       // y,x exact small ints
            float2 f = flow2[(size_t)b * HW_ + src];  // {fx, fy}

            // Bit-exact numpy order: y + ((1 - ts) * f) * 160, no FMA.
            float dt = __fsub_rn(1.0f, e.x);
            float wy = __fadd_rn(e.y, __fmul_rn(__fmul_rn(dt, f.y), 160.0f));
            float wx = __fadd_rn(e.z, __fmul_rn(__fmul_rn(dt, f.x), 160.0f));
            float ry = rintf(wy);                     // round half to even
            float rx = rintf(wx);
            // Validity on rounded floats (-0.0 is valid, like the ref).
            if (ry >= 0.0f && ry < (float)H_ && rx >= 0.0f && rx < (float)W_) {
                int iy = (int)ry, ix = (int)rx;
                unsigned c = (e.w > 0.0f) ? 0u : 1u;  // 0=pos, 1=neg
                unsigned t = (unsigned)(iy * 2 + (ix >= 80));
                pay[k] = (unsigned)src | (c << 15) | ((unsigned)ix << 16)
                       | (t << 24);
                val[k] = true;
                rank[k] = atomicAdd(&cnt[t], 1u);     // LDS rank within block
            }
        }
    }
    __syncthreads();

    // Inclusive prefix scan of cnt[256] (Hillis-Steele, all threads sync).
    if (threadIdx.x < TILES_) scan[threadIdx.x] = cnt[threadIdx.x];
    __syncthreads();
    for (int d = 1; d < TILES_; d <<= 1) {
        unsigned v = 0;
        if (threadIdx.x < TILES_) {
            v = scan[threadIdx.x];
            if ((int)threadIdx.x >= d) v += scan[threadIdx.x - d];
        }
        __syncthreads();
        if (threadIdx.x < TILES_) scan[threadIdx.x] = v;
        __syncthreads();
    }
    // Global reservation per non-empty tile; record total valid events.
    if (threadIdx.x < TILES_) {
        unsigned c = cnt[threadIdx.x];
        base[threadIdx.x] = c ? atomicAdd(&tails[b * TILES_ + threadIdx.x], c)
                              : 0u;
        if (threadIdx.x == TILES_ - 1) stot = scan[TILES_ - 1];
    }
    __syncthreads();

    // LDS scatter into tile-sorted order: slot = exclusive_off(t) + rank.
#pragma unroll
    for (int k = 0; k < 8; ++k) {
        if (val[k]) {
            unsigned t = pay[k] >> 24;
            buf[scan[t] - cnt[t] + rank[k]] = pay[k];
        }
    }
    __syncthreads();

    // Linear flush: consecutive j -> same tile run -> coalesced global store.
    const unsigned tot = stot;
    for (unsigned j = threadIdx.x; j < tot; j += 1024) {
        unsigned p = buf[j];
        unsigned t = p >> 24;
        unsigned pos = base[t] + (j - (scan[t] - cnt[t]));
        if (pos < SEG_CAP_)                           // ~never taken branch
            segs[((size_t)(b * TILES_ + t)) * SEG_CAP_ + pos] = p;
    }
}

// ---------------------------------------------------------------------------
// Pass B: one block per (b, dst tile). Exact dedup hash set on the payload
// key + count/contrib accumulators, all in LDS; fused divide + plain store.
// Termination: <= SEG_CAP_ = HASH_ events => empty slot always reachable.
// ---------------------------------------------------------------------------
__global__ __launch_bounds__(512) void accum_pass(
    const unsigned* __restrict__ tails,
    const unsigned* __restrict__ segs,
    float* __restrict__ out)                          // (B, 2, H, W)
{
    __shared__ unsigned hset[HASH_];                  // 32 KB
    __shared__ unsigned cntl[2 * 80];
    __shared__ unsigned cbl[2 * 80];

    const int bt = blockIdx.x;                        // b*TILES_ + t
    const int b = bt >> 8, t = bt & 255;
    const int row = t >> 1, half = t & 1;

    for (int j = threadIdx.x; j < HASH_; j += 512) hset[j] = EMPTY_;
    if (threadIdx.x < 160) { cntl[threadIdx.x] = 0u; cbl[threadIdx.x] = 0u; }
    __syncthreads();

    const unsigned n = min(tails[bt], (unsigned)SEG_CAP_);
    const unsigned* seg = segs + (size_t)bt * SEG_CAP_;
    volatile unsigned* hv = hset;

    for (unsigned i = threadIdx.x; i < n; i += 512) {
        unsigned key = seg[i];                  // src|pol<<15|x<<16|tile<<24
        unsigned c = (key >> 15) & 1u;
        unsigned x = (key >> 16) & 0xFFu;
        unsigned cl = c * 80 + (x - (unsigned)half * 80u);

        unsigned h = mix32(key) & (HASH_ - 1);
        for (;;) {
            unsigned cur = hv[h];                     // cheap pre-read
            if (cur == key) break;                    // duplicate triple
            if (cur == EMPTY_) {
                unsigned prev = atomicCAS(&hset[h], EMPTY_, key);
                if (prev == EMPTY_) {                 // first (pol,src,fw)
                    atomicAdd(&cbl[cl], 1u);
                    break;
                }
                if (prev == key) break;               // raced duplicate
            }
            h = (h + 1) & (HASH_ - 1);
        }
        atomicAdd(&cntl[cl], 1u);                     // event count
    }
    __syncthreads();

    if (threadIdx.x < 160) {
        unsigned c = threadIdx.x / 80;
        unsigned xl = threadIdx.x % 80;
        unsigned cnt = cntl[threadIdx.x], cb = cbl[threadIdx.x];
        float r = (float)cnt;                         // cnt < 2^24: exact
        if (cb > 0u) r = __fdiv_rn(r, (float)cb);
        out[((size_t)(b * 2 + c)) * HW_ + row * W_ + half * 80 + xl] = r;
    }
}

extern "C" void kernel_launch(void* const* d_in, const int* in_sizes, int n_in,
                              void* d_out, int out_size, void* d_ws, size_t ws_size,
                              hipStream_t stream) {
    const float*  flow = (const float*)d_in[0];
    const float4* ev   = (const float4*)d_in[1];
    // d_in[2] (pol_mask) is redundant with event_list's p column — not read.

    int B = in_sizes[0] / (2 * HW_);          // = 4
    int N = in_sizes[1] / (B * 4);            // = 1,000,000

    // Workspace: [tails u32 x B*TILES_][segs u32 x B*TILES_*SEG_CAP_][flow2]
    unsigned* tails = (unsigned*)d_ws;
    unsigned* segs  = tails + (size_t)B * TILES_;
    float2*   flow2 = (float2*)(segs + (size_t)B * TILES_ * SEG_CAP_);

    hipMemsetAsync(tails, 0, (size_t)B * TILES_ * sizeof(unsigned), stream);

    int total = B * HW_;
    repack_flow<<<(total + 255) / 256, 256, 0, stream>>>(flow, flow2, total);

    dim3 gridA((N + EVB_ - 1) / EVB_, B);
    bin_pass<<<gridA, 1024, 0, stream>>>(ev, flow2, tails, segs, N);

    accum_pass<<<B * TILES_, 512, 0, stream>>>(tails, segs, (float*)d_out);
}

// Round 8
// 146.596 us; speedup vs baseline: 3.2320x; 1.0199x over previous
//
#include <hip/hip_runtime.h>

#define H_ 128
#define W_ 160
#define HW_ (H_ * W_)
#define TILES_ 256        // dst tiles per batch: (row, x-half) = 128 x 2
#define SEG_CAP_ 8192     // events per tile seg: ~2.5x mean (~3300)
#define EVB_ 4096         // events per bin_pass block (512 thr x 8)
#define HASH_ 8192        // LDS hash entries; >= SEG_CAP_ guarantees termination
#define EMPTY_ 0xFFFFFFFFu

__device__ __forceinline__ unsigned mix32(unsigned h) {
    h ^= h >> 16; h *= 0x85ebca6bu;
    h ^= h >> 13; h *= 0xc2b2ae35u;
    h ^= h >> 16;
    return h;
}

// ---------------------------------------------------------------------------
// Pass 0: interleave planar flow -> float2: one 8B gather per event later.
// ---------------------------------------------------------------------------
__global__ __launch_bounds__(256) void repack_flow(
    const float* __restrict__ flow, float2* __restrict__ flow2, int total)
{
    int i = blockIdx.x * blockDim.x + threadIdx.x;
    if (i >= total) return;
    int b = i / HW_, idx = i - b * HW_;
    const float* fl = flow + (size_t)b * 2 * HW_;
    flow2[i] = make_float2(fl[idx], fl[HW_ + idx]);
}

// ---------------------------------------------------------------------------
// Pass A: warp math per event, bin payloads by dst tile. 512-thread blocks,
// launch_bounds(512,8) -> 4 blocks/CU, 32 waves/CU (r5-r7 ran 16-wave blocks
// at 2 blocks/CU, 57-62% occupancy, latency-bound at 1.4 TB/s effective).
// Events prefetched 4-at-a-time for MLP: ev loads overlap flow2 gathers.
// ---------------------------------------------------------------------------
__global__ __launch_bounds__(512, 8) void bin_pass(
    const float4* __restrict__ ev,       // (B, N, 4): ts, y, x, p
    const float2* __restrict__ flow2,    // (B, HW)
    unsigned* __restrict__ tails,        // (B*TILES_), pre-zeroed
    unsigned* __restrict__ segs,         // (B*TILES_, SEG_CAP_)
    int N)
{
    __shared__ unsigned cnt[TILES_];
    __shared__ unsigned base[TILES_];

    const int b = blockIdx.y;
    const int i0 = blockIdx.x * EVB_;
    const float4* evb = ev + (size_t)b * N;
    const float2* flb = flow2 + (size_t)b * HW_;

    for (int j = threadIdx.x; j < TILES_; j += 512) cnt[j] = 0u;
    __syncthreads();

    unsigned pay[8], rank[8];
    unsigned short tt[8];
    bool val[8];

#pragma unroll
    for (int half = 0; half < 2; ++half) {
        float4 e[4];
        int idx[4];
#pragma unroll
        for (int k = 0; k < 4; ++k) {               // batch the stream loads
            idx[k] = i0 + (half * 4 + k) * 512 + (int)threadIdx.x;
            e[k] = (idx[k] < N) ? evb[idx[k]]
                                : make_float4(0.f, 0.f, 0.f, 0.f);
        }
        float2 f[4];
        int src[4];
#pragma unroll
        for (int k = 0; k < 4; ++k) {               // batch the gathers
            src[k] = (int)e[k].y * W_ + (int)e[k].z;
            f[k] = flb[src[k]];
        }
#pragma unroll
        for (int k = 0; k < 4; ++k) {
            int kk = half * 4 + k;
            val[kk] = false;
            if (idx[k] < N) {
                // Bit-exact numpy order: y + ((1 - ts) * f) * 160, no FMA.
                float dt = __fsub_rn(1.0f, e[k].x);
                float wy = __fadd_rn(e[k].y,
                                     __fmul_rn(__fmul_rn(dt, f[k].y), 160.0f));
                float wx = __fadd_rn(e[k].z,
                                     __fmul_rn(__fmul_rn(dt, f[k].x), 160.0f));
                float ry = rintf(wy);               // round half to even
                float rx = rintf(wx);
                // Validity on rounded floats (-0.0 valid, like the ref).
                if (ry >= 0.0f && ry < (float)H_ &&
                    rx >= 0.0f && rx < (float)W_) {
                    int iy = (int)ry, ix = (int)rx;
                    unsigned c = (e[k].w > 0.0f) ? 0u : 1u;
                    unsigned t = (unsigned)(iy * 2 + (ix >= 80));
                    pay[kk] = (unsigned)src[k] | (c << 15)
                            | ((unsigned)ix << 16);
                    tt[kk] = (unsigned short)t;
                    val[kk] = true;
                    rank[kk] = atomicAdd(&cnt[t], 1u);   // LDS rank
                }
            }
        }
    }
    __syncthreads();

    if (threadIdx.x < TILES_) {
        unsigned c = cnt[threadIdx.x];
        base[threadIdx.x] = c ? atomicAdd(&tails[b * TILES_ + threadIdx.x], c)
                              : 0u;
    }
    __syncthreads();

#pragma unroll
    for (int kk = 0; kk < 8; ++kk) {
        if (val[kk]) {
            unsigned pos = base[tt[kk]] + rank[kk];
            if (pos < SEG_CAP_)                      // ~never taken
                segs[((size_t)(b * TILES_ + tt[kk])) * SEG_CAP_ + pos]
                    = pay[kk];
        }
    }
}

// ---------------------------------------------------------------------------
// Pass B: one block per (b, dst tile). Exact dedup hash set on the payload
// key + count/contrib accumulators, all in LDS; fused divide + plain store.
// Termination: <= SEG_CAP_ = HASH_ events => empty slot always reachable.
// ---------------------------------------------------------------------------
__global__ __launch_bounds__(512) void accum_pass(
    const unsigned* __restrict__ tails,
    const unsigned* __restrict__ segs,
    float* __restrict__ out)                          // (B, 2, H, W)
{
    __shared__ unsigned hset[HASH_];                  // 32 KB
    __shared__ unsigned cntl[2 * 80];
    __shared__ unsigned cbl[2 * 80];

    const int bt = blockIdx.x;                        // b*TILES_ + t
    const int b = bt >> 8, t = bt & 255;
    const int row = t >> 1, half = t & 1;

    for (int j = threadIdx.x; j < HASH_; j += 512) hset[j] = EMPTY_;
    if (threadIdx.x < 160) { cntl[threadIdx.x] = 0u; cbl[threadIdx.x] = 0u; }
    __syncthreads();

    const unsigned n = min(tails[bt], (unsigned)SEG_CAP_);
    const unsigned* seg = segs + (size_t)bt * SEG_CAP_;
    volatile unsigned* hv = hset;

    for (unsigned i = threadIdx.x; i < n; i += 512) {
        unsigned key = seg[i];                        // src | pol<<15 | x<<16
        unsigned c = (key >> 15) & 1u;
        unsigned x = (key >> 16) & 0xFFu;
        unsigned cl = c * 80 + (x - (unsigned)half * 80u);

        unsigned h = mix32(key) & (HASH_ - 1);
        for (;;) {
            unsigned cur = hv[h];                     // cheap pre-read
            if (cur == key) break;                    // duplicate triple
            if (cur == EMPTY_) {
                unsigned prev = atomicCAS(&hset[h], EMPTY_, key);
                if (prev == EMPTY_) {                 // first (pol,src,fw)
                    atomicAdd(&cbl[cl], 1u);
                    break;
                }
                if (prev == key) break;               // raced duplicate
            }
            h = (h + 1) & (HASH_ - 1);
        }
        atomicAdd(&cntl[cl], 1u);                     // event count
    }
    __syncthreads();

    if (threadIdx.x < 160) {
        unsigned c = threadIdx.x / 80;
        unsigned xl = threadIdx.x % 80;
        unsigned cnt = cntl[threadIdx.x], cb = cbl[threadIdx.x];
        float r = (float)cnt;                         // cnt < 2^24: exact
        if (cb > 0u) r = __fdiv_rn(r, (float)cb);
        out[((size_t)(b * 2 + c)) * HW_ + row * W_ + half * 80 + xl] = r;
    }
}

extern "C" void kernel_launch(void* const* d_in, const int* in_sizes, int n_in,
                              void* d_out, int out_size, void* d_ws, size_t ws_size,
                              hipStream_t stream) {
    const float*  flow = (const float*)d_in[0];
    const float4* ev   = (const float4*)d_in[1];
    // d_in[2] (pol_mask) is redundant with event_list's p column — not read.

    int B = in_sizes[0] / (2 * HW_);          // = 4
    int N = in_sizes[1] / (B * 4);            // = 1,000,000

    // Workspace: [tails u32 x B*TILES_][segs u32 x B*TILES_*SEG_CAP_][flow2]
    unsigned* tails = (unsigned*)d_ws;
    unsigned* segs  = tails + (size_t)B * TILES_;
    float2*   flow2 = (float2*)(segs + (size_t)B * TILES_ * SEG_CAP_);

    hipMemsetAsync(tails, 0, (size_t)B * TILES_ * sizeof(unsigned), stream);

    int total = B * HW_;
    repack_flow<<<(total + 255) / 256, 256, 0, stream>>>(flow, flow2, total);

    dim3 gridA((N + EVB_ - 1) / EVB_, B);
    bin_pass<<<gridA, 512, 0, stream>>>(ev, flow2, tails, segs, N);

    accum_pass<<<B * TILES_, 512, 0, stream>>>(tails, segs, (float*)d_out);
}